// Round 12
// baseline (651.448 us; speedup 1.0000x reference)
//
#include <hip/hip_runtime.h>
#include <hip/hip_cooperative_groups.h>

namespace cg = cooperative_groups;

// AttentionPooling: N=262144, DIM=256, H=4, HD=64, B=4096 (batch sorted).
// R17 vs R16 (402; G=8 neutral -> 7th refuted attn theory).
//   Re-fitted cost model (fits R8/R13/R16): ~22 us PER KERNEL LAUNCH,
//   fill 160 fixed, attn ~155 (x-delivery pinned ~2.2 TB/s across 7 variants
//   -> platform floor for this shape), prep 12. Largest addressable item:
//   launch+prep plumbing ~34 us.
//   Fix: ONE cooperative kernel (harness-supported): 1024 blocks x 256 thr
//   (4/CU co-resident: LDS 33 KB, VGPR<=128 via launch_bounds(256,4)).
//   Phase1: blocks 0..67 do vwt+qw prep (distributed); ALL blocks binary-
//   search their 5 segment boundaries from sorted batch (offs eliminated);
//   threadfence + grid.sync + fence (G16 XCD non-coherence). Phase2: R13
//   main-loop body VERBATIM x4 consecutive segments + ONE shared coalesced
//   vwT epilogue (vwt traffic /4). Runtime fallback to exact R13 2-dispatch
//   path if cooperative launch errors (capture/occupancy).

constexpr int DIM = 256;
constexpr int NH  = 4;
constexpr int HD  = 64;
constexpr float SCL  = 0.125f;   // HD^-0.5
constexpr float EPSV = 1e-8f;

// workspace layout (float offsets)
constexpr int WS_QW   = 0;       // 1024 floats: folded query.key_w
constexpr int WS_QB   = 1024;    // 4 floats
constexpr int WS_OFFS = 1088;    // B+1 ints (fallback path only)
constexpr int WS_VWT  = 8192;    // 65536 floats: float4[jj=0..63][t=0..255]

// ---- DPP/swizzle reduce: sum over each 32-lane half ----
template<int CTRL>
__device__ __forceinline__ float dpp_ror_add(float v){
  int r = __builtin_amdgcn_update_dpp(0, __float_as_int(v), CTRL, 0xF, 0xF, false);
  return v + __int_as_float(r);
}
__device__ __forceinline__ float red32(float v){
  v = dpp_ror_add<0x121>(v);   // row_ror:1
  v = dpp_ror_add<0x122>(v);   // row_ror:2
  v = dpp_ror_add<0x124>(v);   // row_ror:4
  v = dpp_ror_add<0x128>(v);   // row_ror:8  -> 16-lane row sum
  int r = __builtin_amdgcn_ds_swizzle(__float_as_int(v), 0x401F);  // xor16
  return v + __int_as_float(r);
}

// ================= cooperative single-kernel path =================
__global__ __launch_bounds__(256, 4)
void attn_coop(const float* __restrict__ x,
               const int* __restrict__ batch32,
               const float* __restrict__ query,
               const float* __restrict__ key_w,
               const float* __restrict__ key_b,
               const float* __restrict__ value_w,
               float* __restrict__ ws,
               const float* __restrict__ value_b,
               float* __restrict__ out,
               int N, int B){
  constexpr int G4 = 4;                      // segments per block
  __shared__ __align__(16) float S_all[4][1024];   // 16 KB per-wave partials
  __shared__ __align__(16) float Sfin[G4][1024];   // 16 KB per-segment final S
  __shared__ float sums_all[4][NH];
  __shared__ float invs[G4][NH], wsums[G4][NH];
  __shared__ int offsL[G4 + 1];

  const int bid = blockIdx.x, tid = threadIdx.x;
  const int b0  = bid * G4;

  // ---- phase 1a: distributed prep (blocks 0..67) ----
  if (bid < 64){
    float4 v = *(const float4*)(value_w + (size_t)tid*DIM + 4*bid);  // one-time gather
    ((float4*)(ws + WS_VWT))[bid*256 + tid] = v;                     // coalesced write
  } else if (bid < 68){
    int t = (bid - 64)*256 + tid;   // 0..1023
    int h = t >> 8, j = t & 255;
    float acc = 0.f;
    #pragma unroll 8
    for (int d = 0; d < HD; ++d)
      acc += query[h*HD+d] * key_w[(size_t)(h*HD+d)*DIM + j];
    ws[WS_QW + t] = acc;
    if (j == 0){
      float bb = 0.f;
      for (int d = 0; d < HD; ++d)
        bb += query[h*HD+d] * key_b[h*HD+d];
      ws[WS_QB + h] = bb;
    }
  }

  // ---- phase 1b: per-block segment boundaries via binary search (input-only) ----
  const bool is64 = (batch32[N-1] == 0);   // int64: that int is a high word = 0
  if (tid <= G4){
    const int target = b0 + tid;           // offs[b] = first i with batch[i] >= b
    int lo = 0, hi = N;
    while (lo < hi){
      const int mid = (lo + hi) >> 1;
      const int v = is64 ? batch32[2*(size_t)mid] : batch32[mid];
      if (v < target) lo = mid + 1; else hi = mid;
    }
    offsL[tid] = lo;
  }

  __threadfence();                 // release phase-1 ws writes (cross-XCD)
  cg::this_grid().sync();
  __threadfence();                 // acquire side
  __syncthreads();

  const int wave = tid >> 6, lane = tid & 63;
  const int half = lane >> 5, sl = lane & 31;   // half-wave = one stream
  const int sigma = wave * 2 + half;            // stream id 0..7

  // lane-resident qw fragment: cols [4sl..4sl+3] and [128+4sl..128+4sl+3]
  float qwr[NH][8];
  #pragma unroll
  for (int h = 0; h < NH; ++h){
    float4 a = *(const float4*)(ws + WS_QW + h*DIM + 4*sl);
    float4 c = *(const float4*)(ws + WS_QW + h*DIM + 128 + 4*sl);
    qwr[h][0]=a.x; qwr[h][1]=a.y; qwr[h][2]=a.z; qwr[h][3]=a.w;
    qwr[h][4]=c.x; qwr[h][5]=c.y; qwr[h][6]=c.z; qwr[h][7]=c.w;
  }
  float qb[NH];
  #pragma unroll
  for (int h = 0; h < NH; ++h) qb[h] = ws[WS_QB + h];

  const float4* xr4 = (const float4*)x;   // one row = 64 float4
  const float4 Z = make_float4(0.f, 0.f, 0.f, 0.f);

  for (int g = 0; g < G4; ++g){
    const int s = offsL[g], e = offsL[g+1];

    float Sacc[NH][8];
    #pragma unroll
    for (int h = 0; h < NH; ++h)
      #pragma unroll
      for (int c = 0; c < 8; ++c) Sacc[h][c] = 0.f;
    float se[NH] = {0.f, 0.f, 0.f, 0.f};

    // R13 body: stream sigma does pairs (n0,n0+1), n0 = s+2*sigma+16k; depth-1 prefetch
    int n0 = s + sigma*2;
    bool v0 = n0 < e;
    bool v1 = n0 + 1 < e;
    float4 a0=Z, b0v=Z, a1=Z, b1=Z;
    if (v0){ a0 = xr4[(size_t)n0*64 + sl];     b0v = xr4[(size_t)n0*64 + 32 + sl]; }
    if (v1){ a1 = xr4[(size_t)(n0+1)*64 + sl]; b1  = xr4[(size_t)(n0+1)*64 + 32 + sl]; }

    while (v0){
      const int nn = n0 + 16;
      const bool w0 = nn < e;
      const bool w1 = nn + 1 < e;
      float4 c0=Z, d0=Z, c1=Z, d1=Z;
      if (w0){ c0 = xr4[(size_t)nn*64 + sl];     d0 = xr4[(size_t)nn*64 + 32 + sl]; }
      if (w1){ c1 = xr4[(size_t)(nn+1)*64 + sl]; d1 = xr4[(size_t)(nn+1)*64 + 32 + sl]; }

      float xv0[8] = {a0.x,a0.y,a0.z,a0.w,b0v.x,b0v.y,b0v.z,b0v.w};
      float xv1[8] = {a1.x,a1.y,a1.z,a1.w,b1.x,b1.y,b1.z,b1.w};

      float p0[NH], p1[NH];
      #pragma unroll
      for (int h = 0; h < NH; ++h){
        float s0 = 0.f, s1 = 0.f;
        #pragma unroll
        for (int c = 0; c < 8; ++c){ s0 += qwr[h][c]*xv0[c]; s1 += qwr[h][c]*xv1[c]; }
        p0[h] = s0; p1[h] = s1;
      }
      #pragma unroll
      for (int h = 0; h < NH; ++h){
        p0[h] = red32(p0[h]);
        p1[h] = red32(p1[h]);
      }
      const float g1 = v1 ? 1.f : 0.f;
      #pragma unroll
      for (int h = 0; h < NH; ++h){
        float e0 = __expf((p0[h] + qb[h]) * SCL);
        float e1 = __expf((p1[h] + qb[h]) * SCL) * g1;  // xv1 zeroed when !v1
        se[h] += e0 + e1;
        #pragma unroll
        for (int c = 0; c < 8; ++c)
          Sacc[h][c] += e0*xv0[c] + e1*xv1[c];
      }
      n0 = nn; v0 = w0; v1 = w1;
      a0 = c0; b0v = d0; a1 = c1; b1 = d1;
    }

    // combine the two streams of each wave
    #pragma unroll
    for (int h = 0; h < NH; ++h){
      se[h] += __shfl_xor(se[h], 32, 64);
      #pragma unroll
      for (int c = 0; c < 8; ++c) Sacc[h][c] += __shfl_xor(Sacc[h][c], 32, 64);
    }
    if (half == 0){
      #pragma unroll
      for (int h = 0; h < NH; ++h){
        float4 lo = make_float4(Sacc[h][0], Sacc[h][1], Sacc[h][2], Sacc[h][3]);
        float4 hi = make_float4(Sacc[h][4], Sacc[h][5], Sacc[h][6], Sacc[h][7]);
        *(float4*)&S_all[wave][h*DIM + 4*sl]       = lo;
        *(float4*)&S_all[wave][h*DIM + 128 + 4*sl] = hi;
      }
      if (sl == 0){
        #pragma unroll
        for (int h = 0; h < NH; ++h) sums_all[wave][h] = se[h];
      }
    }
    __syncthreads();

    // reduce 4 wave-copies into Sfin[g]; totals -> invs/wsums
    #pragma unroll
    for (int k = 0; k < 4; ++k){
      const int idx = tid + k*256;
      Sfin[g][idx] = S_all[0][idx] + S_all[1][idx] + S_all[2][idx] + S_all[3][idx];
    }
    if (tid < NH){
      float tot = sums_all[0][tid] + sums_all[1][tid]
                + sums_all[2][tid] + sums_all[3][tid];
      float inv = 1.f / (tot + EPSV);
      invs[g][tid]  = inv;
      wsums[g][tid] = tot * inv;
    }
    __syncthreads();   // S_all reusable for next segment
  }

  // shared COALESCED epilogue: vwt read ONCE per 4 segments.
  const int t = tid, h = t >> 6;                  // h wave-uniform
  const float4* vwt4 = (const float4*)(ws + WS_VWT);
  float acc[G4] = {0.f, 0.f, 0.f, 0.f};
  #pragma unroll 8
  for (int jj = 0; jj < 64; ++jj){
    const float4 w4 = vwt4[jj*256 + t];           // coalesced, L2-resident
    #pragma unroll
    for (int g = 0; g < G4; ++g){
      const float4 s4 = *(const float4*)&Sfin[g][h*256 + 4*jj];  // LDS broadcast
      acc[g] += w4.x*s4.x + w4.y*s4.y + w4.z*s4.z + w4.w*s4.w;
    }
  }
  const float vb = value_b[t];
  #pragma unroll
  for (int g = 0; g < G4; ++g)
    out[(size_t)(b0 + g)*256 + t] = acc[g]*invs[g][h] + wsums[g][h]*vb;
}

// ================= fallback: exact R13 2-dispatch path =================
__global__ void prep_seg(const float* __restrict__ query,
                         const float* __restrict__ key_w,
                         const float* __restrict__ key_b,
                         const float* __restrict__ value_w,
                         const int* __restrict__ batch32,
                         float* __restrict__ ws,
                         int* __restrict__ offs,
                         int N, int B, int do_vwt){
  const int bid = blockIdx.x, tid = threadIdx.x;
  if (bid < 64){
    if (do_vwt){
      float4 v = *(const float4*)(value_w + (size_t)tid*DIM + 4*bid);
      ((float4*)(ws + WS_VWT))[bid*256 + tid] = v;
    }
  } else if (bid < 68){
    int t = (bid - 64)*256 + tid;
    int h = t >> 8, j = t & 255;
    float acc = 0.f;
    #pragma unroll 8
    for (int d = 0; d < HD; ++d)
      acc += query[h*HD+d] * key_w[(size_t)(h*HD+d)*DIM + j];
    ws[WS_QW + t] = acc;
    if (j == 0){
      float bb = 0.f;
      for (int d = 0; d < HD; ++d)
        bb += query[h*HD+d] * key_b[h*HD+d];
      ws[WS_QB + h] = bb;
    }
  } else {
    int i = (bid - 68)*256 + tid;
    if (i >= N) return;
    const bool is64 = (batch32[N-1] == 0);
    int v  = is64 ? batch32[2*i] : batch32[i];
    int vp = (i == 0) ? -1 : (is64 ? batch32[2*(i-1)] : batch32[i-1]);
    for (int b = vp + 1; b <= v; ++b) offs[b] = i;
    if (i == N-1)
      for (int b = v + 1; b <= B; ++b) offs[b] = N;
  }
}

__global__ __launch_bounds__(256, 4)
void attn_fused2(const float* __restrict__ x,
                 const int* __restrict__ offs,
                 const float* __restrict__ ws,
                 const float* __restrict__ value_b,
                 float* __restrict__ out){
  __shared__ __align__(16) float S_all[4][NH*DIM];
  __shared__ __align__(16) float Sfin[NH*DIM];
  __shared__ float sums_all[4][NH];
  __shared__ float invs[NH], wsums[NH];

  const int b   = blockIdx.x;
  const int tid = threadIdx.x;
  const int s = offs[b], e = offs[b+1];

  const int wave = tid >> 6, lane = tid & 63;
  const int half = lane >> 5, sl = lane & 31;
  const int sigma = wave * 2 + half;

  float qwr[NH][8];
  #pragma unroll
  for (int h = 0; h < NH; ++h){
    float4 a = *(const float4*)(ws + WS_QW + h*DIM + 4*sl);
    float4 c = *(const float4*)(ws + WS_QW + h*DIM + 128 + 4*sl);
    qwr[h][0]=a.x; qwr[h][1]=a.y; qwr[h][2]=a.z; qwr[h][3]=a.w;
    qwr[h][4]=c.x; qwr[h][5]=c.y; qwr[h][6]=c.z; qwr[h][7]=c.w;
  }
  float qb[NH];
  #pragma unroll
  for (int h = 0; h < NH; ++h) qb[h] = ws[WS_QB + h];

  float Sacc[NH][8];
  #pragma unroll
  for (int h = 0; h < NH; ++h)
    #pragma unroll
    for (int c = 0; c < 8; ++c) Sacc[h][c] = 0.f;
  float se[NH] = {0.f, 0.f, 0.f, 0.f};

  const float4* xr4 = (const float4*)x;
  const float4 Z = make_float4(0.f, 0.f, 0.f, 0.f);

  int n0 = s + sigma*2;
  bool v0 = n0 < e;
  bool v1 = n0 + 1 < e;
  float4 a0=Z, b0=Z, a1=Z, b1=Z;
  if (v0){ a0 = xr4[(size_t)n0*64 + sl];     b0 = xr4[(size_t)n0*64 + 32 + sl]; }
  if (v1){ a1 = xr4[(size_t)(n0+1)*64 + sl]; b1 = xr4[(size_t)(n0+1)*64 + 32 + sl]; }

  while (v0){
    const int nn = n0 + 16;
    const bool w0 = nn < e;
    const bool w1 = nn + 1 < e;
    float4 c0=Z, d0=Z, c1=Z, d1=Z;
    if (w0){ c0 = xr4[(size_t)nn*64 + sl];     d0 = xr4[(size_t)nn*64 + 32 + sl]; }
    if (w1){ c1 = xr4[(size_t)(nn+1)*64 + sl]; d1 = xr4[(size_t)(nn+1)*64 + 32 + sl]; }

    float xv0[8] = {a0.x,a0.y,a0.z,a0.w,b0.x,b0.y,b0.z,b0.w};
    float xv1[8] = {a1.x,a1.y,a1.z,a1.w,b1.x,b1.y,b1.z,b1.w};

    float p0[NH], p1[NH];
    #pragma unroll
    for (int h = 0; h < NH; ++h){
      float s0 = 0.f, s1 = 0.f;
      #pragma unroll
      for (int c = 0; c < 8; ++c){ s0 += qwr[h][c]*xv0[c]; s1 += qwr[h][c]*xv1[c]; }
      p0[h] = s0; p1[h] = s1;
    }
    #pragma unroll
    for (int h = 0; h < NH; ++h){
      p0[h] = red32(p0[h]);
      p1[h] = red32(p1[h]);
    }
    const float g1 = v1 ? 1.f : 0.f;
    #pragma unroll
    for (int h = 0; h < NH; ++h){
      float e0 = __expf((p0[h] + qb[h]) * SCL);
      float e1 = __expf((p1[h] + qb[h]) * SCL) * g1;
      se[h] += e0 + e1;
      #pragma unroll
      for (int c = 0; c < 8; ++c)
        Sacc[h][c] += e0*xv0[c] + e1*xv1[c];
    }
    n0 = nn; v0 = w0; v1 = w1;
    a0 = c0; b0 = d0; a1 = c1; b1 = d1;
  }

  #pragma unroll
  for (int h = 0; h < NH; ++h){
    se[h] += __shfl_xor(se[h], 32, 64);
    #pragma unroll
    for (int c = 0; c < 8; ++c) Sacc[h][c] += __shfl_xor(Sacc[h][c], 32, 64);
  }
  if (half == 0){
    #pragma unroll
    for (int h = 0; h < NH; ++h){
      float4 lo = make_float4(Sacc[h][0], Sacc[h][1], Sacc[h][2], Sacc[h][3]);
      float4 hi = make_float4(Sacc[h][4], Sacc[h][5], Sacc[h][6], Sacc[h][7]);
      *(float4*)&S_all[wave][h*DIM + 4*sl]       = lo;
      *(float4*)&S_all[wave][h*DIM + 128 + 4*sl] = hi;
    }
    if (sl == 0){
      #pragma unroll
      for (int h = 0; h < NH; ++h) sums_all[wave][h] = se[h];
    }
  }
  __syncthreads();

  #pragma unroll
  for (int k = 0; k < 4; ++k){
    const int idx = tid + k*256;
    Sfin[idx] = S_all[0][idx] + S_all[1][idx] + S_all[2][idx] + S_all[3][idx];
  }
  if (tid < NH){
    float tot = sums_all[0][tid] + sums_all[1][tid]
              + sums_all[2][tid] + sums_all[3][tid];
    float inv = 1.f / (tot + EPSV);
    invs[tid]  = inv;
    wsums[tid] = tot * inv;
  }
  __syncthreads();

  const int t = tid, h = t >> 6;
  const float4* vwt4 = (const float4*)(ws + WS_VWT);
  const float4* sp   = (const float4*)&Sfin[h*256];
  float acc = 0.f;
  #pragma unroll 8
  for (int jj = 0; jj < 64; ++jj){
    const float4 w4 = vwt4[jj*256 + t];
    const float4 s4 = sp[jj];
    acc += w4.x*s4.x + w4.y*s4.y + w4.z*s4.z + w4.w*s4.w;
  }
  out[(size_t)b*256 + t] = acc * invs[h] + wsums[h] * value_b[t];
}

// ---- minimal fused fallback (value_w row gather) for tiny workspace ----
__global__ __launch_bounds__(512, 4)
void attn_pool_fused(const float* __restrict__ x,
                     const int* __restrict__ offs,
                     const float* __restrict__ ws,
                     const float* __restrict__ value_w,
                     const float* __restrict__ value_b,
                     float* __restrict__ out){
  __shared__ __align__(16) float lds[8192 + 32 + 1024 + 512 + 8];
  float* S_all    = lds;
  float* sums_all = lds + 8192;

  const int b   = blockIdx.x;
  const int tid = threadIdx.x;
  const int seg_start = offs[b];
  const int seg_end   = offs[b+1];

  const int wave = tid >> 6, lane = tid & 63;
  const int half = lane >> 5, sl = lane & 31;
  const int sigma = wave * 2 + half;

  float qwr[NH][8];
  #pragma unroll
  for (int h = 0; h < NH; ++h){
    float4 a = *(const float4*)(ws + WS_QW + h*DIM + 4*sl);
    float4 c = *(const float4*)(ws + WS_QW + h*DIM + 128 + 4*sl);
    qwr[h][0]=a.x; qwr[h][1]=a.y; qwr[h][2]=a.z; qwr[h][3]=a.w;
    qwr[h][4]=c.x; qwr[h][5]=c.y; qwr[h][6]=c.z; qwr[h][7]=c.w;
  }
  float qb[NH];
  #pragma unroll
  for (int h = 0; h < NH; ++h) qb[h] = ws[WS_QB + h];

  float Sacc[NH][8];
  #pragma unroll
  for (int h = 0; h < NH; ++h)
    #pragma unroll
    for (int c = 0; c < 8; ++c) Sacc[h][c] = 0.f;
  float se[NH] = {0.f, 0.f, 0.f, 0.f};

  const float4* xr4 = (const float4*)x;
  const float4 Z = make_float4(0.f,0.f,0.f,0.f);

  int n0 = seg_start + sigma*2;
  bool v0 = n0 < seg_end;
  bool v1 = n0 + 1 < seg_end;
  float4 a0=Z, b0=Z, a1=Z, b1=Z;
  if (v0){ a0 = xr4[(size_t)n0*64 + sl];     b0 = xr4[(size_t)n0*64 + 32 + sl]; }
  if (v1){ a1 = xr4[(size_t)(n0+1)*64 + sl]; b1 = xr4[(size_t)(n0+1)*64 + 32 + sl]; }

  while (v0){
    const int nn = n0 + 32;
    const bool w0 = nn < seg_end;
    const bool w1 = nn + 1 < seg_end;
    float4 c0=Z, d0=Z, c1=Z, d1=Z;
    if (w0){ c0 = xr4[(size_t)nn*64 + sl];     d0 = xr4[(size_t)nn*64 + 32 + sl]; }
    if (w1){ c1 = xr4[(size_t)(nn+1)*64 + sl]; d1 = xr4[(size_t)(nn+1)*64 + 32 + sl]; }

    float xv0[8] = {a0.x,a0.y,a0.z,a0.w,b0.x,b0.y,b0.z,b0.w};
    float xv1[8] = {a1.x,a1.y,a1.z,a1.w,b1.x,b1.y,b1.z,b1.w};

    float p0[NH], p1[NH];
    #pragma unroll
    for (int h = 0; h < NH; ++h){
      float s0 = 0.f, s1 = 0.f;
      #pragma unroll
      for (int c = 0; c < 8; ++c){ s0 += qwr[h][c]*xv0[c]; s1 += qwr[h][c]*xv1[c]; }
      p0[h] = s0; p1[h] = s1;
    }
    #pragma unroll
    for (int m = 1; m < 32; m <<= 1){
      #pragma unroll
      for (int h = 0; h < NH; ++h){
        p0[h] += __shfl_xor(p0[h], m, 64);
        p1[h] += __shfl_xor(p1[h], m, 64);
      }
    }
    const float g1 = v1 ? 1.f : 0.f;
    #pragma unroll
    for (int h = 0; h < NH; ++h){
      float e0 = __expf((p0[h] + qb[h]) * SCL);
      float e1 = __expf((p1[h] + qb[h]) * SCL) * g1;
      se[h] += e0 + e1;
      #pragma unroll
      for (int c = 0; c < 8; ++c)
        Sacc[h][c] += e0*xv0[c] + e1*xv1[c];
    }
    n0 = nn; v0 = w0; v1 = w1;
    a0 = c0; b0 = d0; a1 = c1; b1 = d1;
  }

  #pragma unroll
  for (int h = 0; h < NH; ++h){
    se[h] += __shfl_xor(se[h], 32, 64);
    #pragma unroll
    for (int c = 0; c < 8; ++c) Sacc[h][c] += __shfl_xor(Sacc[h][c], 32, 64);
  }
  if (half == 0){
    #pragma unroll
    for (int h = 0; h < NH; ++h){
      float4 lo = make_float4(Sacc[h][0], Sacc[h][1], Sacc[h][2], Sacc[h][3]);
      float4 hi = make_float4(Sacc[h][4], Sacc[h][5], Sacc[h][6], Sacc[h][7]);
      *(float4*)&S_all[wave*1024 + h*DIM + 4*sl]       = lo;
      *(float4*)&S_all[wave*1024 + h*DIM + 128 + 4*sl] = hi;
    }
    if (sl == 0){
      #pragma unroll
      for (int h = 0; h < NH; ++h) sums_all[wave*4 + h] = se[h];
    }
  }
  __syncthreads();

  float* Sfin  = lds + 8224;
  float* invs  = lds + 9760;
  float* wsums = invs + 4;
  #pragma unroll
  for (int k = 0; k < 2; ++k){
    const int idx = tid + k*512;
    float sv = 0.f;
    #pragma unroll
    for (int w = 0; w < 8; ++w) sv += S_all[w*1024 + idx];
    Sfin[idx] = sv;
  }
  if (tid < NH){
    float tot = 0.f;
    #pragma unroll
    for (int w = 0; w < 8; ++w) tot += sums_all[w*4 + tid];
    float inv = 1.f / (tot + EPSV);
    invs[tid] = inv; wsums[tid] = tot * inv;
  }
  __syncthreads();

  float* ep2 = lds + 9248;
  const int t = tid & 255, part = tid >> 8;
  const int h2 = t >> 6;
  const float4* vrow = (const float4*)(value_w + (size_t)t * DIM) + part*32;
  const float4* sp   = (const float4*)&Sfin[h2*256] + part*32;
  float acc = 0.f;
  #pragma unroll
  for (int q = 0; q < 32; ++q){
    float4 r = vrow[q];
    float4 sv = sp[q];
    acc += r.x*sv.x + r.y*sv.y + r.z*sv.z + r.w*sv.w;
  }
  ep2[part*256 + t] = acc;
  __syncthreads();
  if (part == 0)
    out[(size_t)b * DIM + t] = (ep2[t] + ep2[256 + t]) * invs[h2] + wsums[h2] * value_b[t];
}

extern "C" void kernel_launch(void* const* d_in, const int* in_sizes, int n_in,
                              void* d_out, int out_size, void* d_ws, size_t ws_size,
                              hipStream_t stream){
  const float* x       = (const float*)d_in[0];
  const int*   batch   = (const int*)d_in[1];
  const float* query   = (const float*)d_in[2];
  const float* key_w   = (const float*)d_in[3];
  const float* key_b   = (const float*)d_in[4];
  const float* value_w = (const float*)d_in[5];
  const float* value_b = (const float*)d_in[6];
  float* ws  = (float*)d_ws;
  float* out = (float*)d_out;

  int N = in_sizes[1];        // 262144
  int B = out_size / DIM;     // 4096

  const size_t need_vwt = ((size_t)WS_VWT + 65536) * sizeof(float);
  const int do_vwt = (ws_size >= need_vwt) ? 1 : 0;

  // ---- preferred: single cooperative kernel ----
  bool coop_done = false;
  if (do_vwt && (B % 4) == 0 && (B / 4) <= 1024){
    const float* xa = x;  const int* ba = batch;  const float* qa = query;
    const float* kwa = key_w;  const float* kba = key_b;  const float* vwa = value_w;
    float* wsa = ws;  const float* vba = value_b;  float* oa = out;
    int Na = N, Ba = B;
    void* args[] = {&xa, &ba, &qa, &kwa, &kba, &vwa, &wsa, &vba, &oa, &Na, &Ba};
    hipError_t st = hipLaunchCooperativeKernel((const void*)attn_coop,
                                               dim3(B / 4), dim3(256),
                                               args, 0, stream);
    coop_done = (st == hipSuccess);
  }

  if (!coop_done){
    // fallback: exact R13 2-dispatch path
    int* offs = (int*)(ws + WS_OFFS);
    const int seg_blocks = (N + 255) / 256;
    prep_seg<<<68 + seg_blocks, 256, 0, stream>>>(query, key_w, key_b, value_w,
                                                  batch, ws, offs, N, B, do_vwt);
    if (do_vwt)
      attn_fused2<<<B, 256, 0, stream>>>(x, offs, ws, value_b, out);
    else
      attn_pool_fused<<<B, 512, 0, stream>>>(x, offs, ws, value_w, value_b, out);
  }
}

// Round 13
// 413.564 us; speedup vs baseline: 1.5752x; 1.5752x over previous
//
#include <hip/hip_runtime.h>

// AttentionPooling: N=262144, DIM=256, H=4, HD=64, B=4096 (batch sorted).
// R18 vs R17 (651 FAILED: cooperative launch costs ~2x dispatch overhead
//            (no graph replay) AND grid-sync shape cut delivery to 0.46 TB/s.
//            Reverted. 8th refuted theory.)
//   18-round fit: attn x-delivery pinned ~2.2 TB/s vs ALL structural levers;
//   R13 budget = fill 160 (fixed) + attn ~155 + prep ~10 + ~20us x 3 dispatch
//   boundaries. Only addressable: plumbing -> ONE regular kernel.
//   R18: self-contained single dispatch, 512 blocks x 512 thr, G=8 segments
//   (R16's proven body). Per block: binary-search 9 offsets from sorted batch;
//   fold qw into LDS itself (wave-coalesced over j at fixed d; key_w L2-hot
//   after first touch, ~4us aggregate); main loop x8; ONE epilogue reading
//   value_w rows directly amortized 8x (~14us aggregate vs R0's 110us).
//   Zero ws use on main path. LDS 68.8 KB -> 2 blocks/CU = 16 waves/CU
//   (= R13); launch_bounds(512,4) = 128 VGPR cap (R8/R14 spill lesson).

constexpr int DIM = 256;
constexpr int NH  = 4;
constexpr int HD  = 64;
constexpr float SCL  = 0.125f;   // HD^-0.5
constexpr float EPSV = 1e-8f;

// workspace layout (fallback path only)
constexpr int WS_QW   = 0;
constexpr int WS_QB   = 1024;
constexpr int WS_OFFS = 1088;

// ---- DPP/swizzle reduce: sum over each 32-lane half ----
template<int CTRL>
__device__ __forceinline__ float dpp_ror_add(float v){
  int r = __builtin_amdgcn_update_dpp(0, __float_as_int(v), CTRL, 0xF, 0xF, false);
  return v + __int_as_float(r);
}
__device__ __forceinline__ float red32(float v){
  v = dpp_ror_add<0x121>(v);   // row_ror:1
  v = dpp_ror_add<0x122>(v);   // row_ror:2
  v = dpp_ror_add<0x124>(v);   // row_ror:4
  v = dpp_ror_add<0x128>(v);   // row_ror:8  -> 16-lane row sum
  int r = __builtin_amdgcn_ds_swizzle(__float_as_int(v), 0x401F);  // xor16
  return v + __int_as_float(r);
}

// ================= single self-contained kernel =================
__global__ __launch_bounds__(512, 4)
void attn_all(const float* __restrict__ x,
              const int* __restrict__ batch32,
              const float* __restrict__ query,
              const float* __restrict__ key_w,
              const float* __restrict__ key_b,
              const float* __restrict__ value_w,
              const float* __restrict__ value_b,
              float* __restrict__ out,
              int N, int B){
  constexpr int G8 = 8;                            // segments per block
  __shared__ __align__(16) float S_all[8][1024];   // 32 KB; aliased as ep later
  __shared__ __align__(16) float Sfin[G8][1024];   // 32 KB
  __shared__ __align__(16) float qwL[1024];        // 4 KB folded qw
  __shared__ float qbL[NH];
  __shared__ float sums_all[8][NH];
  __shared__ float invs[G8][NH], wsums[G8][NH];
  __shared__ int offsL[G8 + 1];

  const int bid = blockIdx.x, tid = threadIdx.x;
  const int b0  = bid * G8;

  // ---- per-block segment boundaries: binary search on sorted batch ----
  const bool is64 = (batch32[N-1] == 0);   // int64: that int is a high word = 0
  if (tid <= G8){
    const int target = b0 + tid;           // first i with batch[i] >= target
    int lo = 0, hi = N;
    while (lo < hi){
      const int mid = (lo + hi) >> 1;
      const int v = is64 ? batch32[2*(size_t)mid] : batch32[mid];
      if (v < target) lo = mid + 1; else hi = mid;
    }
    offsL[tid] = lo;
  }

  // ---- in-block qw fold: qw[h][j] = sum_d query[h,d]*key_w[h*64+d, j] ----
  // wave-coalesced: at fixed d, consecutive j across lanes. key_w L2-hot.
  for (int idx = tid; idx < 1024; idx += 512){
    const int h = idx >> 8, j = idx & 255;
    float acc = 0.f;
    #pragma unroll 8
    for (int d = 0; d < HD; ++d)
      acc += query[h*HD+d] * key_w[(size_t)(h*HD+d)*DIM + j];
    qwL[idx] = acc;
  }
  if (tid < NH){
    float bb = 0.f;
    for (int d = 0; d < HD; ++d)
      bb += query[tid*HD+d] * key_b[tid*HD+d];
    qbL[tid] = bb;
  }
  __syncthreads();

  const int wave = tid >> 6, lane = tid & 63;
  const int half = lane >> 5, sl = lane & 31;   // half-wave = one stream
  const int sigma = wave * 2 + half;            // stream id 0..15

  // lane-resident qw fragment: cols [4sl..4sl+3] and [128+4sl..128+4sl+3]
  float qwr[NH][8];
  #pragma unroll
  for (int h = 0; h < NH; ++h){
    float4 a = *(const float4*)&qwL[h*DIM + 4*sl];
    float4 c = *(const float4*)&qwL[h*DIM + 128 + 4*sl];
    qwr[h][0]=a.x; qwr[h][1]=a.y; qwr[h][2]=a.z; qwr[h][3]=a.w;
    qwr[h][4]=c.x; qwr[h][5]=c.y; qwr[h][6]=c.z; qwr[h][7]=c.w;
  }
  float qb[NH];
  #pragma unroll
  for (int h = 0; h < NH; ++h) qb[h] = qbL[h];

  const float4* xr4 = (const float4*)x;   // one row = 64 float4
  const float4 Z = make_float4(0.f, 0.f, 0.f, 0.f);

  for (int g = 0; g < G8; ++g){
    const int s = offsL[g], e = offsL[g+1];

    float Sacc[NH][8];
    #pragma unroll
    for (int h = 0; h < NH; ++h)
      #pragma unroll
      for (int c = 0; c < 8; ++c) Sacc[h][c] = 0.f;
    float se[NH] = {0.f, 0.f, 0.f, 0.f};

    // stream sigma: node pairs (n0,n0+1), n0 = s + 2*sigma + 32k; depth-1 prefetch
    int n0 = s + sigma*2;
    bool v0 = n0 < e;
    bool v1 = n0 + 1 < e;
    float4 la0=Z, lb0=Z, la1=Z, lb1=Z;
    if (v0){ la0 = xr4[(size_t)n0*64 + sl];     lb0 = xr4[(size_t)n0*64 + 32 + sl]; }
    if (v1){ la1 = xr4[(size_t)(n0+1)*64 + sl]; lb1 = xr4[(size_t)(n0+1)*64 + 32 + sl]; }

    while (v0){
      const int nn = n0 + 32;
      const bool w0 = nn < e;
      const bool w1 = nn + 1 < e;
      float4 nc0=Z, nd0=Z, nc1=Z, nd1=Z;
      if (w0){ nc0 = xr4[(size_t)nn*64 + sl];     nd0 = xr4[(size_t)nn*64 + 32 + sl]; }
      if (w1){ nc1 = xr4[(size_t)(nn+1)*64 + sl]; nd1 = xr4[(size_t)(nn+1)*64 + 32 + sl]; }

      float xv0[8] = {la0.x,la0.y,la0.z,la0.w,lb0.x,lb0.y,lb0.z,lb0.w};
      float xv1[8] = {la1.x,la1.y,la1.z,la1.w,lb1.x,lb1.y,lb1.z,lb1.w};

      float p0[NH], p1[NH];
      #pragma unroll
      for (int h = 0; h < NH; ++h){
        float s0 = 0.f, s1 = 0.f;
        #pragma unroll
        for (int c = 0; c < 8; ++c){ s0 += qwr[h][c]*xv0[c]; s1 += qwr[h][c]*xv1[c]; }
        p0[h] = s0; p1[h] = s1;
      }
      // 8 independent 32-lane reduces: 4 DPP stages (VALU) + 1 ds_swizzle
      #pragma unroll
      for (int h = 0; h < NH; ++h){
        p0[h] = red32(p0[h]);
        p1[h] = red32(p1[h]);
      }
      const float g1 = v1 ? 1.f : 0.f;
      #pragma unroll
      for (int h = 0; h < NH; ++h){
        float e0 = __expf((p0[h] + qb[h]) * SCL);
        float e1 = __expf((p1[h] + qb[h]) * SCL) * g1;  // xv1 zeroed when !v1
        se[h] += e0 + e1;
        #pragma unroll
        for (int c = 0; c < 8; ++c)
          Sacc[h][c] += e0*xv0[c] + e1*xv1[c];
      }
      n0 = nn; v0 = w0; v1 = w1;
      la0 = nc0; lb0 = nd0; la1 = nc1; lb1 = nd1;
    }

    // combine the two streams of each wave (same columns, different rows)
    #pragma unroll
    for (int h = 0; h < NH; ++h){
      se[h] += __shfl_xor(se[h], 32, 64);
      #pragma unroll
      for (int c = 0; c < 8; ++c) Sacc[h][c] += __shfl_xor(Sacc[h][c], 32, 64);
    }
    if (half == 0){
      #pragma unroll
      for (int h = 0; h < NH; ++h){
        float4 lo = make_float4(Sacc[h][0], Sacc[h][1], Sacc[h][2], Sacc[h][3]);
        float4 hi = make_float4(Sacc[h][4], Sacc[h][5], Sacc[h][6], Sacc[h][7]);
        *(float4*)&S_all[wave][h*DIM + 4*sl]       = lo;
        *(float4*)&S_all[wave][h*DIM + 128 + 4*sl] = hi;
      }
      if (sl == 0){
        #pragma unroll
        for (int h = 0; h < NH; ++h) sums_all[wave][h] = se[h];
      }
    }
    __syncthreads();

    // reduce 8 wave-copies into Sfin[g]; totals -> invs/wsums
    #pragma unroll
    for (int k2 = 0; k2 < 2; ++k2){
      const int idx = tid + k2*512;
      float sv = 0.f;
      #pragma unroll
      for (int w = 0; w < 8; ++w) sv += S_all[w][idx];
      Sfin[g][idx] = sv;
    }
    if (tid < NH){
      float tot = 0.f;
      #pragma unroll
      for (int w = 0; w < 8; ++w) tot += sums_all[w][tid];
      float inv = 1.f / (tot + EPSV);
      invs[g][tid]  = inv;
      wsums[g][tid] = tot * inv;
    }
    __syncthreads();   // S_all reusable for next segment
  }

  // ---- shared epilogue: value_w row read amortized over 8 segments ----
  // thread (t,part): part covers 32 float4 of row t; 8 accs (one/segment).
  const int t = tid & 255, part = tid >> 8, h = t >> 6;
  const float4* vrow = (const float4*)(value_w + (size_t)t * DIM) + part*32;
  float acc[G8];
  #pragma unroll
  for (int g = 0; g < G8; ++g) acc[g] = 0.f;

  for (int q = 0; q < 32; ++q){
    const float4 r = vrow[q];
    const int jj = part*32 + q;
    #pragma unroll
    for (int g = 0; g < G8; ++g){
      const float4 s4 = *(const float4*)&Sfin[g][h*256 + 4*jj];  // LDS broadcast
      acc[g] += r.x*s4.x + r.y*s4.y + r.z*s4.z + r.w*s4.w;
    }
  }
  float* ep = &S_all[0][0];   // alias: [2][G8][256] = 16 KB
  #pragma unroll
  for (int g = 0; g < G8; ++g) ep[(part*G8 + g)*256 + t] = acc[g];
  __syncthreads();
  if (part == 0){
    const float vb = value_b[t];
    #pragma unroll
    for (int g = 0; g < G8; ++g){
      out[(size_t)(b0 + g)*256 + t] =
          (ep[g*256 + t] + ep[(G8 + g)*256 + t]) * invs[g][h] + wsums[g][h] * vb;
    }
  }
}

// ================= fallback: 2-dispatch path (B%8 != 0 only) =================
__global__ void prep_seg(const float* __restrict__ query,
                         const float* __restrict__ key_w,
                         const float* __restrict__ key_b,
                         const int* __restrict__ batch32,
                         float* __restrict__ ws,
                         int* __restrict__ offs,
                         int N, int B){
  const int bid = blockIdx.x, tid = threadIdx.x;
  if (bid < 4){
    int t = bid*256 + tid;
    int h = t >> 8, j = t & 255;
    float acc = 0.f;
    #pragma unroll 8
    for (int d = 0; d < HD; ++d)
      acc += query[h*HD+d] * key_w[(size_t)(h*HD+d)*DIM + j];
    ws[WS_QW + t] = acc;
    if (j == 0){
      float bb = 0.f;
      for (int d = 0; d < HD; ++d)
        bb += query[h*HD+d] * key_b[h*HD+d];
      ws[WS_QB + h] = bb;
    }
  } else {
    int i = (bid - 4)*256 + tid;
    if (i >= N) return;
    const bool is64 = (batch32[N-1] == 0);
    int v  = is64 ? batch32[2*i] : batch32[i];
    int vp = (i == 0) ? -1 : (is64 ? batch32[2*(i-1)] : batch32[i-1]);
    for (int b = vp + 1; b <= v; ++b) offs[b] = i;
    if (i == N-1)
      for (int b = v + 1; b <= B; ++b) offs[b] = N;
  }
}

__global__ __launch_bounds__(512, 4)
void attn_pool_fused(const float* __restrict__ x,
                     const int* __restrict__ offs,
                     const float* __restrict__ ws,
                     const float* __restrict__ value_w,
                     const float* __restrict__ value_b,
                     float* __restrict__ out){
  __shared__ __align__(16) float lds[8192 + 32 + 1024 + 512 + 8];
  float* S_all    = lds;
  float* sums_all = lds + 8192;

  const int b   = blockIdx.x;
  const int tid = threadIdx.x;
  const int seg_start = offs[b];
  const int seg_end   = offs[b+1];

  const int wave = tid >> 6, lane = tid & 63;
  const int half = lane >> 5, sl = lane & 31;
  const int sigma = wave * 2 + half;

  float qwr[NH][8];
  #pragma unroll
  for (int h = 0; h < NH; ++h){
    float4 a = *(const float4*)(ws + WS_QW + h*DIM + 4*sl);
    float4 c = *(const float4*)(ws + WS_QW + h*DIM + 128 + 4*sl);
    qwr[h][0]=a.x; qwr[h][1]=a.y; qwr[h][2]=a.z; qwr[h][3]=a.w;
    qwr[h][4]=c.x; qwr[h][5]=c.y; qwr[h][6]=c.z; qwr[h][7]=c.w;
  }
  float qb[NH];
  #pragma unroll
  for (int h = 0; h < NH; ++h) qb[h] = ws[WS_QB + h];

  float Sacc[NH][8];
  #pragma unroll
  for (int h = 0; h < NH; ++h)
    #pragma unroll
    for (int c = 0; c < 8; ++c) Sacc[h][c] = 0.f;
  float se[NH] = {0.f, 0.f, 0.f, 0.f};

  const float4* xr4 = (const float4*)x;
  const float4 Z = make_float4(0.f,0.f,0.f,0.f);

  int n0 = seg_start + sigma*2;
  bool v0 = n0 < seg_end;
  bool v1 = n0 + 1 < seg_end;
  float4 a0=Z, b0=Z, a1=Z, b1=Z;
  if (v0){ a0 = xr4[(size_t)n0*64 + sl];     b0 = xr4[(size_t)n0*64 + 32 + sl]; }
  if (v1){ a1 = xr4[(size_t)(n0+1)*64 + sl]; b1 = xr4[(size_t)(n0+1)*64 + 32 + sl]; }

  while (v0){
    const int nn = n0 + 32;
    const bool w0 = nn < seg_end;
    const bool w1 = nn + 1 < seg_end;
    float4 c0=Z, d0=Z, c1=Z, d1=Z;
    if (w0){ c0 = xr4[(size_t)nn*64 + sl];     d0 = xr4[(size_t)nn*64 + 32 + sl]; }
    if (w1){ c1 = xr4[(size_t)(nn+1)*64 + sl]; d1 = xr4[(size_t)(nn+1)*64 + 32 + sl]; }

    float xv0[8] = {a0.x,a0.y,a0.z,a0.w,b0.x,b0.y,b0.z,b0.w};
    float xv1[8] = {a1.x,a1.y,a1.z,a1.w,b1.x,b1.y,b1.z,b1.w};

    float p0[NH], p1[NH];
    #pragma unroll
    for (int h = 0; h < NH; ++h){
      float s0 = 0.f, s1 = 0.f;
      #pragma unroll
      for (int c = 0; c < 8; ++c){ s0 += qwr[h][c]*xv0[c]; s1 += qwr[h][c]*xv1[c]; }
      p0[h] = s0; p1[h] = s1;
    }
    #pragma unroll
    for (int h = 0; h < NH; ++h){
      p0[h] = red32(p0[h]);
      p1[h] = red32(p1[h]);
    }
    const float g1 = v1 ? 1.f : 0.f;
    #pragma unroll
    for (int h = 0; h < NH; ++h){
      float e0 = __expf((p0[h] + qb[h]) * SCL);
      float e1 = __expf((p1[h] + qb[h]) * SCL) * g1;
      se[h] += e0 + e1;
      #pragma unroll
      for (int c = 0; c < 8; ++c)
        Sacc[h][c] += e0*xv0[c] + e1*xv1[c];
    }
    n0 = nn; v0 = w0; v1 = w1;
    a0 = c0; b0 = d0; a1 = c1; b1 = d1;
  }

  #pragma unroll
  for (int h = 0; h < NH; ++h){
    se[h] += __shfl_xor(se[h], 32, 64);
    #pragma unroll
    for (int c = 0; c < 8; ++c) Sacc[h][c] += __shfl_xor(Sacc[h][c], 32, 64);
  }
  if (half == 0){
    #pragma unroll
    for (int h = 0; h < NH; ++h){
      float4 lo = make_float4(Sacc[h][0], Sacc[h][1], Sacc[h][2], Sacc[h][3]);
      float4 hi = make_float4(Sacc[h][4], Sacc[h][5], Sacc[h][6], Sacc[h][7]);
      *(float4*)&S_all[wave*1024 + h*DIM + 4*sl]       = lo;
      *(float4*)&S_all[wave*1024 + h*DIM + 128 + 4*sl] = hi;
    }
    if (sl == 0){
      #pragma unroll
      for (int h = 0; h < NH; ++h) sums_all[wave*4 + h] = se[h];
    }
  }
  __syncthreads();

  float* Sfin  = lds + 8224;
  float* invs  = lds + 9760;
  float* wsums = invs + 4;
  #pragma unroll
  for (int k = 0; k < 2; ++k){
    const int idx = tid + k*512;
    float sv = 0.f;
    #pragma unroll
    for (int w = 0; w < 8; ++w) sv += S_all[w*1024 + idx];
    Sfin[idx] = sv;
  }
  if (tid < NH){
    float tot = 0.f;
    #pragma unroll
    for (int w = 0; w < 8; ++w) tot += sums_all[w*4 + tid];
    float inv = 1.f / (tot + EPSV);
    invs[tid] = inv; wsums[tid] = tot * inv;
  }
  __syncthreads();

  float* ep2 = lds + 9248;
  const int t = tid & 255, part = tid >> 8;
  const int h2 = t >> 6;
  const float4* vrow = (const float4*)(value_w + (size_t)t * DIM) + part*32;
  const float4* sp   = (const float4*)&Sfin[h2*256] + part*32;
  float acc = 0.f;
  #pragma unroll
  for (int q = 0; q < 32; ++q){
    float4 r = vrow[q];
    float4 sv = sp[q];
    acc += r.x*sv.x + r.y*sv.y + r.z*sv.z + r.w*sv.w;
  }
  ep2[part*256 + t] = acc;
  __syncthreads();
  if (part == 0)
    out[(size_t)b * DIM + t] = (ep2[t] + ep2[256 + t]) * invs[h2] + wsums[h2] * value_b[t];
}

extern "C" void kernel_launch(void* const* d_in, const int* in_sizes, int n_in,
                              void* d_out, int out_size, void* d_ws, size_t ws_size,
                              hipStream_t stream){
  const float* x       = (const float*)d_in[0];
  const int*   batch   = (const int*)d_in[1];
  const float* query   = (const float*)d_in[2];
  const float* key_w   = (const float*)d_in[3];
  const float* key_b   = (const float*)d_in[4];
  const float* value_w = (const float*)d_in[5];
  const float* value_b = (const float*)d_in[6];
  float* ws  = (float*)d_ws;
  float* out = (float*)d_out;

  int N = in_sizes[1];        // 262144
  int B = out_size / DIM;     // 4096

  if ((B % 8) == 0){
    // single self-contained dispatch (no workspace use)
    attn_all<<<B / 8, 512, 0, stream>>>(x, batch, query, key_w, key_b,
                                        value_w, value_b, out, N, B);
  } else {
    int* offs = (int*)(ws + WS_OFFS);
    const int seg_blocks = (N + 255) / 256;
    prep_seg<<<4 + seg_blocks, 256, 0, stream>>>(query, key_w, key_b,
                                                 batch, ws, offs, N, B);
    attn_pool_fused<<<B, 512, 0, stream>>>(x, offs, ws, value_w, value_b, out);
  }
}

// Round 14
// 392.930 us; speedup vs baseline: 1.6579x; 1.0525x over previous
//
#include <hip/hip_runtime.h>

// AttentionPooling: N=262144, DIM=256, H=4, HD=64, B=4096 (batch sorted).
// R19 = clean revert to R13 (best measured: 393.8 us).
//   R18 (single self-contained dispatch) FAILED pre-committed falsifier
//   (413.6 >= 390): saved ~20us launch boundary but paid more in in-block
//   qw-fold + value_w-gather epilogue + 2 blocks/CU (68.8 KB LDS).
//   Nine structural theories tested and refuted across R6-R18: occupancy,
//   line coalescing, shuffle-chain cost (x2), execution shape (x2),
//   streaming+atomics, register depth, LDS dbuf, async global_load_lds dbuf,
//   segment batching (x4, x8), cooperative and regular single-dispatch.
//   attn x-delivery pinned ~2.2 TB/s throughout. R13's configuration is the
//   empirical optimum: 2 dispatches (prep_seg + attn_fused2), ws-staged
//   vwt/qw, 256-thr block per segment, DPP+ds_swizzle reduce, fused
//   COALESCED vwT epilogue. Remaining budget: fill 160 (harness re-poison,
//   fixed) + attn ~150 + prep/boundaries ~80 -> practical floor.

constexpr int DIM = 256;
constexpr int NH  = 4;
constexpr int HD  = 64;
constexpr float SCL  = 0.125f;   // HD^-0.5
constexpr float EPSV = 1e-8f;

// workspace layout (float offsets)
constexpr int WS_QW   = 0;       // 1024 floats: folded query.key_w
constexpr int WS_QB   = 1024;    // 4 floats
constexpr int WS_OFFS = 1088;    // B+1 ints (4097 ints, ends < 8192 floats)
constexpr int WS_VWT  = 8192;    // 65536 floats: float4[jj=0..63][t=0..255]

// ---- DPP/swizzle reduce helpers: sum over a 32-lane group ----
// 4x row_ror (within 16-lane rows, VALU pipe) + 1x ds_swizzle xor16.
template<int CTRL>
__device__ __forceinline__ float dpp_ror_add(float v){
  int r = __builtin_amdgcn_update_dpp(0, __float_as_int(v), CTRL, 0xF, 0xF, false);
  return v + __int_as_float(r);
}
__device__ __forceinline__ float red32(float v){
  v = dpp_ror_add<0x121>(v);   // row_ror:1
  v = dpp_ror_add<0x122>(v);   // row_ror:2
  v = dpp_ror_add<0x124>(v);   // row_ror:4
  v = dpp_ror_add<0x128>(v);   // row_ror:8  -> full 16-lane row sum
  int r = __builtin_amdgcn_ds_swizzle(__float_as_int(v), 0x401F);  // xor16
  return v + __int_as_float(r);
}

// ---- merged prep: [0,64) vwt transpose, [64,68) qw fold, [68,..) seg offsets ----
__global__ void prep_seg(const float* __restrict__ query,
                         const float* __restrict__ key_w,
                         const float* __restrict__ key_b,
                         const float* __restrict__ value_w,
                         const int* __restrict__ batch32,
                         float* __restrict__ ws,
                         int* __restrict__ offs,
                         int N, int B, int do_vwt){
  const int bid = blockIdx.x, tid = threadIdx.x;
  if (bid < 64){
    if (do_vwt){
      float4 v = *(const float4*)(value_w + (size_t)tid*DIM + 4*bid);  // one-time gather
      ((float4*)(ws + WS_VWT))[bid*256 + tid] = v;                     // coalesced write
    }
  } else if (bid < 68){
    int t = (bid - 64)*256 + tid;     // 0..1023
    int h = t >> 8, j = t & 255;
    float acc = 0.f;
    #pragma unroll 8
    for (int d = 0; d < HD; ++d)
      acc += query[h*HD+d] * key_w[(size_t)(h*HD+d)*DIM + j];
    ws[WS_QW + t] = acc;
    if (j == 0){
      float bb = 0.f;
      for (int d = 0; d < HD; ++d)
        bb += query[h*HD+d] * key_b[h*HD+d];
      ws[WS_QB + h] = bb;
    }
  } else {
    int i = (bid - 68)*256 + tid;
    if (i >= N) return;
    const bool is64 = (batch32[N-1] == 0);   // int64: that int is a high word = 0
    int v  = is64 ? batch32[2*i] : batch32[i];
    int vp = (i == 0) ? -1 : (is64 ? batch32[2*(i-1)] : batch32[i-1]);
    for (int b = vp + 1; b <= v; ++b) offs[b] = i;
    if (i == N-1)
      for (int b = v + 1; b <= B; ++b) offs[b] = N;
  }
}

// ---- main: one block (256 thr = 8 half-wave streams) per segment, fused epilogue ----
__global__ __launch_bounds__(256, 4)
void attn_fused2(const float* __restrict__ x,
                 const int* __restrict__ offs,
                 const float* __restrict__ ws,
                 const float* __restrict__ value_b,
                 float* __restrict__ out){
  __shared__ __align__(16) float S_all[4][NH*DIM];   // 16 KB per-wave partial S
  __shared__ __align__(16) float Sfin[NH*DIM];       // 4 KB
  __shared__ float sums_all[4][NH];
  __shared__ float invs[NH], wsums[NH];

  const int b   = blockIdx.x;
  const int tid = threadIdx.x;
  const int s = offs[b], e = offs[b+1];

  const int wave = tid >> 6, lane = tid & 63;
  const int half = lane >> 5, sl = lane & 31;   // half-wave = one stream
  const int sigma = wave * 2 + half;            // stream id 0..7

  // lane-resident qw fragment: cols [4sl..4sl+3] and [128+4sl..128+4sl+3]
  float qwr[NH][8];
  #pragma unroll
  for (int h = 0; h < NH; ++h){
    float4 a = *(const float4*)(ws + WS_QW + h*DIM + 4*sl);
    float4 c = *(const float4*)(ws + WS_QW + h*DIM + 128 + 4*sl);
    qwr[h][0]=a.x; qwr[h][1]=a.y; qwr[h][2]=a.z; qwr[h][3]=a.w;
    qwr[h][4]=c.x; qwr[h][5]=c.y; qwr[h][6]=c.z; qwr[h][7]=c.w;
  }
  float qb[NH];
  #pragma unroll
  for (int h = 0; h < NH; ++h) qb[h] = ws[WS_QB + h];

  float Sacc[NH][8];
  #pragma unroll
  for (int h = 0; h < NH; ++h)
    #pragma unroll
    for (int c = 0; c < 8; ++c) Sacc[h][c] = 0.f;
  float se[NH] = {0.f, 0.f, 0.f, 0.f};

  const float4* xr4 = (const float4*)x;   // one row = 64 float4
  const float4 Z = make_float4(0.f, 0.f, 0.f, 0.f);

  // stream sigma: node pairs (n0, n0+1), n0 = s + 2*sigma + 16k; depth-1 prefetch
  int n0 = s + sigma*2;
  bool v0 = n0 < e;
  bool v1 = n0 + 1 < e;
  float4 a0=Z, b0=Z, a1=Z, b1=Z;
  if (v0){ a0 = xr4[(size_t)n0*64 + sl];     b0 = xr4[(size_t)n0*64 + 32 + sl]; }
  if (v1){ a1 = xr4[(size_t)(n0+1)*64 + sl]; b1 = xr4[(size_t)(n0+1)*64 + 32 + sl]; }

  while (v0){
    const int nn = n0 + 16;
    const bool w0 = nn < e;
    const bool w1 = nn + 1 < e;
    float4 c0=Z, d0=Z, c1=Z, d1=Z;
    if (w0){ c0 = xr4[(size_t)nn*64 + sl];     d0 = xr4[(size_t)nn*64 + 32 + sl]; }
    if (w1){ c1 = xr4[(size_t)(nn+1)*64 + sl]; d1 = xr4[(size_t)(nn+1)*64 + 32 + sl]; }

    float xv0[8] = {a0.x,a0.y,a0.z,a0.w,b0.x,b0.y,b0.z,b0.w};
    float xv1[8] = {a1.x,a1.y,a1.z,a1.w,b1.x,b1.y,b1.z,b1.w};

    float p0[NH], p1[NH];
    #pragma unroll
    for (int h = 0; h < NH; ++h){
      float s0 = 0.f, s1 = 0.f;
      #pragma unroll
      for (int c = 0; c < 8; ++c){ s0 += qwr[h][c]*xv0[c]; s1 += qwr[h][c]*xv1[c]; }
      p0[h] = s0; p1[h] = s1;
    }
    // 8 independent 32-lane reduces: 4 DPP stages (VALU) + 1 ds_swizzle each
    #pragma unroll
    for (int h = 0; h < NH; ++h){
      p0[h] = red32(p0[h]);
      p1[h] = red32(p1[h]);
    }
    const float g1 = v1 ? 1.f : 0.f;
    #pragma unroll
    for (int h = 0; h < NH; ++h){
      float e0 = __expf((p0[h] + qb[h]) * SCL);
      float e1 = __expf((p1[h] + qb[h]) * SCL) * g1;  // xv1 zeroed when !v1
      se[h] += e0 + e1;
      #pragma unroll
      for (int c = 0; c < 8; ++c)
        Sacc[h][c] += e0*xv0[c] + e1*xv1[c];
    }
    n0 = nn; v0 = w0; v1 = w1;
    a0 = c0; b0 = d0; a1 = c1; b1 = d1;
  }

  // combine the two streams of each wave (same columns, different nodes)
  #pragma unroll
  for (int h = 0; h < NH; ++h){
    se[h] += __shfl_xor(se[h], 32, 64);
    #pragma unroll
    for (int c = 0; c < 8; ++c) Sacc[h][c] += __shfl_xor(Sacc[h][c], 32, 64);
  }
  if (half == 0){
    #pragma unroll
    for (int h = 0; h < NH; ++h){
      float4 lo = make_float4(Sacc[h][0], Sacc[h][1], Sacc[h][2], Sacc[h][3]);
      float4 hi = make_float4(Sacc[h][4], Sacc[h][5], Sacc[h][6], Sacc[h][7]);
      *(float4*)&S_all[wave][h*DIM + 4*sl]       = lo;
      *(float4*)&S_all[wave][h*DIM + 128 + 4*sl] = hi;
    }
    if (sl == 0){
      #pragma unroll
      for (int h = 0; h < NH; ++h) sums_all[wave][h] = se[h];
    }
  }
  __syncthreads();

  // reduce 4 wave-copies into Sfin; totals -> invs/wsums
  #pragma unroll
  for (int k = 0; k < 4; ++k){
    const int idx = tid + k*256;
    Sfin[idx] = S_all[0][idx] + S_all[1][idx] + S_all[2][idx] + S_all[3][idx];
  }
  if (tid < NH){
    float tot = sums_all[0][tid] + sums_all[1][tid]
              + sums_all[2][tid] + sums_all[3][tid];
    float inv = 1.f / (tot + EPSV);
    invs[tid]  = inv;
    wsums[tid] = tot * inv;
  }
  __syncthreads();

  // fused COALESCED epilogue: thread t owns out[b,t]; vwt4[jj*256+t] is
  // 1 KB/instr coalesced and L2-resident; Sfin reads are wave-broadcast.
  const int t = tid, h = t >> 6;                  // h wave-uniform
  const float4* vwt4 = (const float4*)(ws + WS_VWT);
  const float4* sp   = (const float4*)&Sfin[h*256];
  float acc = 0.f;
  #pragma unroll 8
  for (int jj = 0; jj < 64; ++jj){
    const float4 w4 = vwt4[jj*256 + t];
    const float4 s4 = sp[jj];
    acc += w4.x*s4.x + w4.y*s4.y + w4.z*s4.z + w4.w*s4.w;
  }
  out[(size_t)b*256 + t] = acc * invs[h] + wsums[h] * value_b[t];
}

// ---- minimal fused fallback (value_w row gather) for tiny workspace ----
__global__ __launch_bounds__(512, 4)
void attn_pool_fused(const float* __restrict__ x,
                     const int* __restrict__ offs,
                     const float* __restrict__ ws,
                     const float* __restrict__ value_w,
                     const float* __restrict__ value_b,
                     float* __restrict__ out){
  __shared__ __align__(16) float lds[8192 + 32 + 1024 + 512 + 8];
  float* S_all    = lds;          // [8][4][256]
  float* sums_all = lds + 8192;   // [8][4]

  const int b   = blockIdx.x;
  const int tid = threadIdx.x;
  const int seg_start = offs[b];
  const int seg_end   = offs[b+1];

  const int wave = tid >> 6, lane = tid & 63;
  const int half = lane >> 5, sl = lane & 31;
  const int sigma = wave * 2 + half;

  float qwr[NH][8];
  #pragma unroll
  for (int h = 0; h < NH; ++h){
    float4 a = *(const float4*)(ws + WS_QW + h*DIM + 4*sl);
    float4 c = *(const float4*)(ws + WS_QW + h*DIM + 128 + 4*sl);
    qwr[h][0]=a.x; qwr[h][1]=a.y; qwr[h][2]=a.z; qwr[h][3]=a.w;
    qwr[h][4]=c.x; qwr[h][5]=c.y; qwr[h][6]=c.z; qwr[h][7]=c.w;
  }
  float qb[NH];
  #pragma unroll
  for (int h = 0; h < NH; ++h) qb[h] = ws[WS_QB + h];

  float Sacc[NH][8];
  #pragma unroll
  for (int h = 0; h < NH; ++h)
    #pragma unroll
    for (int c = 0; c < 8; ++c) Sacc[h][c] = 0.f;
  float se[NH] = {0.f, 0.f, 0.f, 0.f};

  const float4* xr4 = (const float4*)x;
  const float4 Z = make_float4(0.f,0.f,0.f,0.f);

  int n0 = seg_start + sigma*2;
  bool v0 = n0 < seg_end;
  bool v1 = n0 + 1 < seg_end;
  float4 a0=Z, b0=Z, a1=Z, b1=Z;
  if (v0){ a0 = xr4[(size_t)n0*64 + sl];     b0 = xr4[(size_t)n0*64 + 32 + sl]; }
  if (v1){ a1 = xr4[(size_t)(n0+1)*64 + sl]; b1 = xr4[(size_t)(n0+1)*64 + 32 + sl]; }

  while (v0){
    const int nn = n0 + 32;
    const bool w0 = nn < seg_end;
    const bool w1 = nn + 1 < seg_end;
    float4 c0=Z, d0=Z, c1=Z, d1=Z;
    if (w0){ c0 = xr4[(size_t)nn*64 + sl];     d0 = xr4[(size_t)nn*64 + 32 + sl]; }
    if (w1){ c1 = xr4[(size_t)(nn+1)*64 + sl]; d1 = xr4[(size_t)(nn+1)*64 + 32 + sl]; }

    float xv0[8] = {a0.x,a0.y,a0.z,a0.w,b0.x,b0.y,b0.z,b0.w};
    float xv1[8] = {a1.x,a1.y,a1.z,a1.w,b1.x,b1.y,b1.z,b1.w};

    float p0[NH], p1[NH];
    #pragma unroll
    for (int h = 0; h < NH; ++h){
      float s0 = 0.f, s1 = 0.f;
      #pragma unroll
      for (int c = 0; c < 8; ++c){ s0 += qwr[h][c]*xv0[c]; s1 += qwr[h][c]*xv1[c]; }
      p0[h] = s0; p1[h] = s1;
    }
    #pragma unroll
    for (int m = 1; m < 32; m <<= 1){
      #pragma unroll
      for (int h = 0; h < NH; ++h){
        p0[h] += __shfl_xor(p0[h], m, 64);
        p1[h] += __shfl_xor(p1[h], m, 64);
      }
    }
    const float g1 = v1 ? 1.f : 0.f;
    #pragma unroll
    for (int h = 0; h < NH; ++h){
      float e0 = __expf((p0[h] + qb[h]) * SCL);
      float e1 = __expf((p1[h] + qb[h]) * SCL) * g1;
      se[h] += e0 + e1;
      #pragma unroll
      for (int c = 0; c < 8; ++c)
        Sacc[h][c] += e0*xv0[c] + e1*xv1[c];
    }
    n0 = nn; v0 = w0; v1 = w1;
    a0 = c0; b0 = d0; a1 = c1; b1 = d1;
  }

  #pragma unroll
  for (int h = 0; h < NH; ++h){
    se[h] += __shfl_xor(se[h], 32, 64);
    #pragma unroll
    for (int c = 0; c < 8; ++c) Sacc[h][c] += __shfl_xor(Sacc[h][c], 32, 64);
  }
  if (half == 0){
    #pragma unroll
    for (int h = 0; h < NH; ++h){
      float4 lo = make_float4(Sacc[h][0], Sacc[h][1], Sacc[h][2], Sacc[h][3]);
      float4 hi = make_float4(Sacc[h][4], Sacc[h][5], Sacc[h][6], Sacc[h][7]);
      *(float4*)&S_all[wave*1024 + h*DIM + 4*sl]       = lo;
      *(float4*)&S_all[wave*1024 + h*DIM + 128 + 4*sl] = hi;
    }
    if (sl == 0){
      #pragma unroll
      for (int h = 0; h < NH; ++h) sums_all[wave*4 + h] = se[h];
    }
  }
  __syncthreads();

  float* Sfin  = lds + 8224;
  float* invs  = lds + 9760;
  float* wsums = invs + 4;
  #pragma unroll
  for (int k = 0; k < 2; ++k){
    const int idx = tid + k*512;
    float sv = 0.f;
    #pragma unroll
    for (int w = 0; w < 8; ++w) sv += S_all[w*1024 + idx];
    Sfin[idx] = sv;
  }
  if (tid < NH){
    float tot = 0.f;
    #pragma unroll
    for (int w = 0; w < 8; ++w) tot += sums_all[w*4 + tid];
    float inv = 1.f / (tot + EPSV);
    invs[tid] = inv; wsums[tid] = tot * inv;
  }
  __syncthreads();

  float* ep2 = lds + 9248;
  const int t = tid & 255, part = tid >> 8;
  const int h2 = t >> 6;
  const float4* vrow = (const float4*)(value_w + (size_t)t * DIM) + part*32;
  const float4* sp   = (const float4*)&Sfin[h2*256] + part*32;
  float acc = 0.f;
  #pragma unroll
  for (int q = 0; q < 32; ++q){
    float4 r = vrow[q];
    float4 sv = sp[q];
    acc += r.x*sv.x + r.y*sv.y + r.z*sv.z + r.w*sv.w;
  }
  ep2[part*256 + t] = acc;
  __syncthreads();
  if (part == 0)
    out[(size_t)b * DIM + t] = (ep2[t] + ep2[256 + t]) * invs[h2] + wsums[h2] * value_b[t];
}

extern "C" void kernel_launch(void* const* d_in, const int* in_sizes, int n_in,
                              void* d_out, int out_size, void* d_ws, size_t ws_size,
                              hipStream_t stream){
  const float* x       = (const float*)d_in[0];
  const int*   batch   = (const int*)d_in[1];
  const float* query   = (const float*)d_in[2];
  const float* key_w   = (const float*)d_in[3];
  const float* key_b   = (const float*)d_in[4];
  const float* value_w = (const float*)d_in[5];
  const float* value_b = (const float*)d_in[6];
  float* ws  = (float*)d_ws;
  float* out = (float*)d_out;

  const int N = in_sizes[1];        // 262144
  const int B = out_size / DIM;     // 4096

  int* offs = (int*)(ws + WS_OFFS);

  const size_t need_vwt = ((size_t)WS_VWT + 65536) * sizeof(float);
  const int do_vwt = (ws_size >= need_vwt) ? 1 : 0;

  const int seg_blocks = (N + 255) / 256;
  prep_seg<<<68 + seg_blocks, 256, 0, stream>>>(query, key_w, key_b, value_w,
                                                batch, ws, offs, N, B, do_vwt);
  if (do_vwt)
    attn_fused2<<<B, 256, 0, stream>>>(x, offs, ws, value_b, out);
  else
    attn_pool_fused<<<B, 512, 0, stream>>>(x, offs, ws, value_w, value_b, out);
}